// Round 2
// baseline (13444.197 us; speedup 1.0000x reference)
//
#include <hip/hip_runtime.h>
#include <hip/hip_bf16.h>

#define T_STEPS 512
#define BATCH   256
#define DIN     256
#define DHID    256
#define DCOMB   512
#define NALL    1024     // 4 gates * DHID
#define BBLK    16       // batch rows per workgroup
#define NWG     16       // BATCH / BBLK
#define NTHREADS 1024    // 16 waves
#define KT      16       // K tiles of 32 over DCOMB
#define NT_W    4        // n-tiles (of 16) per wave: 64 ntiles / 16 waves

typedef short bf16_t;
typedef __attribute__((ext_vector_type(4))) short short4v;
typedef __attribute__((ext_vector_type(8))) short short8;
typedef __attribute__((ext_vector_type(4))) float f32x4;

#define APAD 8
#define AROW (DCOMB + APAD)   // 520 bf16 -> 1040 B row stride (16B aligned)

// theta layout: TH[row][seg][17], row = gate*16+b (64 rows), seg 0..15 of 16
// row stride 276 floats (276 mod 32 = 20): cumprod lanes (row, s) hit banks
// (20*row + 17*s + j) mod 32 -> <=3-way; MFMA writes (row step 4 -> +80 = +16
// banks) -> 2-way (free).
#define THSEG 17
#define THR   276             // 16*17 + 4 pad

// LDS carve (bytes)
#define OFF_A0   0
#define SZ_A     (BBLK * AROW * 2)            // 16640 each
#define OFF_A1   (OFF_A0 + SZ_A)
#define OFF_TH   (OFF_A1 + SZ_A)              // 33280
#define SZ_TH    (64 * THR * 4)               // 70656
#define OFF_SEG  (OFF_TH + SZ_TH)
#define SZ_SEG   (64 * 17 * 4)                // 4352
#define LDS_TOTAL (OFF_SEG + SZ_SEG)          // 108288

__device__ inline short f2bf(float f) {
  union { float f; unsigned u; } v; v.f = f;
  unsigned r = (v.u + 0x7FFFu + ((v.u >> 16) & 1u)) >> 16;
  return (short)r;
}

__device__ inline float fast_sigmoid(float x) {
  return 1.f / (1.f + __expf(-x));
}

__device__ inline float fast_tanh(float x) {
  float ax = fabsf(x);
  float e = __expf(2.f * ax);             // inf-safe: 1 - 2/inf = 1
  float r = 1.f - 2.f / (e + 1.f);
  return copysignf(r, x);
}

// Pack W into MFMA-B-fragment order: elem[((nt*16+kt)*64+lane)*8 + j] =
// bf16( W[gate][nrow][k] ), n = nt*16+(lane&15), gate=n>>8, nrow=n&255,
// k = kt*32 + (lane>>4)*8 + j.  Also pack bias[1024] and temps[4].
__global__ __launch_bounds__(256) void pack_w(
    const float* __restrict__ Wf, const float* __restrict__ Wi,
    const float* __restrict__ Wg, const float* __restrict__ Wo,
    const float* __restrict__ bf_, const float* __restrict__ bi_,
    const float* __restrict__ bg_, const float* __restrict__ bo_,
    const float* __restrict__ tf_, const float* __restrict__ ti_,
    const float* __restrict__ tg_, const float* __restrict__ to_,
    bf16_t* __restrict__ Wp, float* __restrict__ bias,
    float* __restrict__ temps)
{
  int tid = blockIdx.x * 256 + threadIdx.x;   // 65536 threads
  int lane = tid & 63;
  int kt = (tid >> 6) & 15;
  int nt = tid >> 10;
  int n = nt * 16 + (lane & 15);
  int gate = n >> 8, nrow = n & 255;
  int k = kt * 32 + (lane >> 4) * 8;
  const float* W = gate == 0 ? Wf : gate == 1 ? Wi : gate == 2 ? Wg : Wo;
  const float* src = W + nrow * DCOMB + k;
  short8 d;
#pragma unroll
  for (int j = 0; j < 8; ++j) d[j] = f2bf(src[j]);
  *(short8*)(Wp + (size_t)tid * 8) = d;

  if (tid < NALL) {
    int g2 = tid >> 8;
    const float* bs = g2 == 0 ? bf_ : g2 == 1 ? bi_ : g2 == 2 ? bg_ : bo_;
    bias[tid] = bs[tid & 255];
  }
  if (tid < 4) {
    const float* ts = tid == 0 ? tf_ : tid == 1 ? ti_ : tid == 2 ? tg_ : to_;
    temps[tid] = ts[0];
  }
}

__global__ __launch_bounds__(NTHREADS, 4) void qlstm_rec(
    const float* __restrict__ x,      // [T, B, DIN]
    const bf16_t* __restrict__ Wp,    // packed bf16 W (B-frag order)
    const float* __restrict__ bias,   // [1024]
    const float* __restrict__ temps,  // [4]
    float* __restrict__ out)          // [T*B*DHID + 2*B*DHID]
{
  extern __shared__ char smem[];
  bf16_t* Abuf0 = (bf16_t*)(smem + OFF_A0);  // [BBLK][AROW] comb (x|h) bf16
  bf16_t* Abuf1 = (bf16_t*)(smem + OFF_A1);
  float* TH  = (float*)(smem + OFF_TH);      // [64][16][17] theta -> act
  float* seg = (float*)(smem + OFF_SEG);     // [64][17] segment products

  const int tid  = threadIdx.x;
  const int wave = tid >> 6, lane = tid & 63;
  const int b0   = blockIdx.x * BBLK;

  // ---- load W fragments into VGPRs (resident across the whole t-loop) ----
  // wave owns n-range [wave*64, wave*64+64): ntiles wave*4+i, i=0..3
  short8 wv[NT_W][KT];
#pragma unroll
  for (int i = 0; i < NT_W; ++i)
#pragma unroll
    for (int kt = 0; kt < KT; ++kt)
      wv[i][kt] = *(const short8*)(Wp +
          ((((size_t)(wave * NT_W + i) * KT + kt) * 64 + lane) * 8));

  float bn[NT_W];
#pragma unroll
  for (int i = 0; i < NT_W; ++i)
    bn[i] = bias[wave * 64 + i * 16 + (lane & 15)];

  // cumprod / update constants
  const float invt = 1.f / temps[tid >> 8];   // gate of this thread's rows
  const bool  isg  = ((tid >> 8) == 2);       // tanh gate

  // MFMA A-fragment coordinates: lane holds A[lane&15][(lane>>4)*8 + j]
  const int arow  = lane & 15;
  const int acol0 = (lane >> 4) * 8;

  // cumprod mapping: 16 threads per (gate,b) row, 16-elem segments
  const int crow = tid >> 4;          // 0..63 = gate*16 + b
  const int cs   = tid & 15;
  float* rp = TH + crow * THR + cs * THSEG;

  // cell state in registers: thread owns (b,kk) for idx = tid + 1024*j
  float creg[4];
#pragma unroll
  for (int j = 0; j < 4; ++j) creg[j] = 0.f;

  // ---- prologue: x(0) -> A0, h(0)=0 ----
  {
    int r = tid >> 6, c0 = (tid & 63) * 4;
    const float4 v = *(const float4*)(x + ((size_t)(b0 + r)) * DIN + c0);
    short4v d;
    d[0] = f2bf(v.x); d[1] = f2bf(v.y); d[2] = f2bf(v.z); d[3] = f2bf(v.w);
    *(short4v*)&Abuf0[r * AROW + c0] = d;
  }
#pragma unroll
  for (int j = 0; j < 4; ++j) {
    int idx = tid + NTHREADS * j;
    Abuf0[(idx >> 8) * AROW + DIN + (idx & 255)] = 0;
  }
  __syncthreads();

  bf16_t* Acur = Abuf0;
  bf16_t* Anxt = Abuf1;

  for (int t = 0; t < T_STEPS; ++t) {
    // ---- 0. prefetch x(t+1) (issued early, consumed after GEMM) ----
    const int xr_ = tid >> 6, xc_ = (tid & 63) * 4;
    const int tp1 = (t + 1 < T_STEPS) ? t + 1 : t;
    const float4 xv = *(const float4*)(
        x + ((size_t)tp1 * BATCH + b0 + xr_) * DIN + xc_);

    // ---- 1. GEMM: theta[16, n-slice] = A[16,512] @ W^T, W in VGPRs ----
    f32x4 acc[NT_W];
#pragma unroll
    for (int i = 0; i < NT_W; ++i) acc[i] = (f32x4){0.f, 0.f, 0.f, 0.f};
#pragma unroll
    for (int kt = 0; kt < KT; ++kt) {
      short8 a = *(const short8*)&Acur[arow * AROW + kt * 32 + acol0];
#pragma unroll
      for (int i = 0; i < NT_W; ++i)
        acc[i] = __builtin_amdgcn_mfma_f32_16x16x32_bf16(a, wv[i][kt], acc[i], 0, 0, 0);
    }

    // ---- 2. cos(theta + bias) -> TH (C/D: col=lane&15, row=(lane>>4)*4+r) --
#pragma unroll
    for (int i = 0; i < NT_W; ++i) {
      // n = wave*64 + i*16 + (lane&15); kk = n&255; gate = wave>>2
      int segi = (wave & 3) * 4 + i;          // kk>>4
      int base = (wave >> 2) * 16 * THR + segi * THSEG + (lane & 15);
      int brow = (lane >> 4) * 4;
#pragma unroll
      for (int r = 0; r < 4; ++r)
        TH[base + (brow + r) * THR] = __cosf(acc[i][r] + bn[i]);
    }

    // ---- 2b. write prefetched x(t+1) into A[nxt] ----
    {
      short4v d;
      d[0] = f2bf(xv.x); d[1] = f2bf(xv.y); d[2] = f2bf(xv.z); d[3] = f2bf(xv.w);
      *(short4v*)&Anxt[xr_ * AROW + xc_] = d;
    }
    __syncthreads();  // S2: TH complete

    // ---- 3a. cumprod pass 1: 16-elem segment products ----
    {
      float p = 1.f;
#pragma unroll
      for (int j = 0; j < 16; ++j) p *= rp[j];
      seg[crow * 17 + cs] = p;
    }
    __syncthreads();  // S3

    // ---- 3b. cumprod pass 2: prefix, /temp, activation, in place ----
    {
      float pre = 1.f;
      for (int j = 0; j < cs; ++j) pre *= seg[crow * 17 + j];
      float run = pre;
#pragma unroll
      for (int j = 0; j < 16; ++j) {
        run *= rp[j];
        float v = run * invt;
        rp[j] = isg ? fast_tanh(v) : fast_sigmoid(v);
      }
    }
    __syncthreads();  // S4: activations ready

    // ---- 4. cell update: c = f*c + i*g; h = o*tanh(c) ----
#pragma unroll
    for (int j = 0; j < 4; ++j) {
      int idx = tid + NTHREADS * j;     // 0..4095
      int b = idx >> 8, kk = idx & 255;
      int tb = b * THR + (kk >> 4) * THSEG + (kk & 15);
      float fv = TH[(0 * 16) * THR + tb];
      float iv = TH[(1 * 16) * THR + tb];
      float gv = TH[(2 * 16) * THR + tb];
      float ov = TH[(3 * 16) * THR + tb];
      float c  = fv * creg[j] + iv * gv;
      creg[j] = c;
      float h = ov * fast_tanh(c);
      out[((size_t)t * BATCH + b0 + b) * DHID + kk] = h;
      Anxt[b * AROW + DIN + kk] = f2bf(h);
      if (t == T_STEPS - 1) {
        out[((size_t)T_STEPS * BATCH + b0 + b) * DHID + kk] = h;          // hx
        out[((size_t)T_STEPS * BATCH + BATCH + b0 + b) * DHID + kk] = c;  // cx
      }
    }
    __syncthreads();  // S5: A[nxt] complete

    bf16_t* tmp = Acur; Acur = Anxt; Anxt = tmp;
  }
}

extern "C" void kernel_launch(void* const* d_in, const int* in_sizes, int n_in,
                              void* d_out, int out_size, void* d_ws, size_t ws_size,
                              hipStream_t stream) {
  const float* x   = (const float*)d_in[0];
  const float* Wf  = (const float*)d_in[1];
  const float* bf_ = (const float*)d_in[2];
  const float* tf_ = (const float*)d_in[3];
  const float* Wi  = (const float*)d_in[4];
  const float* bi_ = (const float*)d_in[5];
  const float* ti_ = (const float*)d_in[6];
  const float* Wg  = (const float*)d_in[7];
  const float* bg_ = (const float*)d_in[8];
  const float* tg_ = (const float*)d_in[9];
  const float* Wo  = (const float*)d_in[10];
  const float* bo_ = (const float*)d_in[11];
  const float* to_ = (const float*)d_in[12];

  bf16_t* Wp   = (bf16_t*)d_ws;                           // 1 MB packed W
  float* bias  = (float*)((char*)d_ws + (1 << 20));        // 4 KB
  float* temps = (float*)((char*)d_ws + (1 << 20) + 4096); // 16 B

  hipLaunchKernelGGL(pack_w, dim3(256), dim3(256), 0, stream,
                     Wf, Wi, Wg, Wo, bf_, bi_, bg_, bo_, tf_, ti_, tg_, to_,
                     Wp, bias, temps);

  // >64KB dynamic LDS: opt in (no-op if already set; not a stream op)
  (void)hipFuncSetAttribute((const void*)qlstm_rec,
                            hipFuncAttributeMaxDynamicSharedMemorySize,
                            LDS_TOTAL);

  hipLaunchKernelGGL(qlstm_rec, dim3(NWG), dim3(NTHREADS), LDS_TOTAL, stream,
                     x, Wp, bias, temps, (float*)d_out);
}